// Round 3
// baseline (3719.897 us; speedup 1.0000x reference)
//
#include <hip/hip_runtime.h>
#include <math.h>

#define TT 1024
#define NCLS 5

__launch_bounds__(256, 2)
__global__ void ar_lstm_seq(const float* __restrict__ x,
                            const float* __restrict__ W_ih,
                            const float* __restrict__ W_hh,
                            const float* __restrict__ b_ih,
                            const float* __restrict__ b_hh,
                            const float* __restrict__ W_fc,
                            const float* __restrict__ b_fc,
                            const float* __restrict__ emb,
                            float* __restrict__ out) {
#pragma clang fp contract(off)
    const int tid  = threadIdx.x;
    const int g    = tid;
    const int lane = tid & 63;
    const int wave = tid >> 6;
    const int b0   = blockIdx.x * 2;

    __shared__ float xs[2][2][64];    // [buf][batch][j]
    __shared__ float hs[2][64];
    __shared__ float gb[2][256];
    __shared__ float embs[6][64];     // row 5 = zeros (t=0 "prev")
    __shared__ float wfcT[64][8];     // transposed W_fc, padded stride
    __shared__ float bfcs[8];
    __shared__ int   sIdx[2];

    // ---- per-thread weights (registers, statically indexed) ----
    float wx[128], wh[64];
#pragma unroll
    for (int j = 0; j < 128; ++j) wx[j] = W_ih[(size_t)g * 128 + j];
#pragma unroll
    for (int j = 0; j < 64; ++j)  wh[j] = W_hh[(size_t)g * 64 + j];
    const float bih = b_ih[g];
    const float bhh = b_hh[g];

    // ---- stage shared constants ----
    if (tid < 64) {
#pragma unroll
        for (int c = 0; c < NCLS; ++c) {
            embs[c][tid] = emb[c * 64 + tid];
            wfcT[tid][c] = W_fc[c * 64 + tid];
        }
        embs[5][tid] = 0.0f;
    }
    if (tid < NCLS) bfcs[tid] = b_fc[tid];

    // ---- prologue: h0 = 0, x[.,0,.], idx = 5 (zero prev) ----
    if (tid < 64)        hs[0][tid] = 0.0f;
    else if (tid < 128)  hs[1][tid - 64] = 0.0f;
    if (tid < 64)        xs[0][0][tid] = x[((size_t)b0 * TT) * 64 + tid];
    else if (tid < 128)  xs[0][1][tid - 64] = x[((size_t)(b0 + 1) * TT) * 64 + tid - 64];
    if (tid == 0) { sIdx[0] = 5; sIdx[1] = 5; }

    float cst = 0.0f;   // cell state, tail waves 0/1, lane j = unit j
    __syncthreads();

    for (int t = 0; t < TT; ++t) {
        const int cb = t & 1, nb = cb ^ 1;

        // prefetch next x into registers (waves 2/3), store after barrier A
        float xn = 0.0f;
        if (t + 1 < TT) {
            if (wave == 2) xn = x[((size_t)b0 * TT + t + 1) * 64 + lane];
            else if (wave == 3) xn = x[((size_t)(b0 + 1) * TT + t + 1) * 64 + lane];
        }

        const int i0 = sIdx[0], i1 = sIdx[1];
        const float* __restrict__ xv0 = &xs[cb][0][0];
        const float* __restrict__ xv1 = &xs[cb][1][0];
        const float* __restrict__ pv0 = &embs[i0][0];
        const float* __restrict__ pv1 = &embs[i1][0];

        // ---- gates: strictly sequential-k fp32 FMA chains, BLAS-like ----
        float s0 = 0.0f, s1 = 0.0f;
#pragma unroll
        for (int j = 0; j < 64; ++j) {          // x part (concat cols 0..63)
            s0 = fmaf(wx[j], xv0[j], s0);
            s1 = fmaf(wx[j], xv1[j], s1);
        }
#pragma unroll
        for (int j = 0; j < 64; ++j) {          // prev part (cols 64..127)
            s0 = fmaf(wx[64 + j], pv0[j], s0);
            s1 = fmaf(wx[64 + j], pv1[j], s1);
        }
        s0 = s0 + bih;                          // (inp@W_ih.T + b_ih)
        s1 = s1 + bih;
        float t0 = 0.0f, t1 = 0.0f;
#pragma unroll
        for (int j = 0; j < 64; ++j) {          // h @ W_hh.T
            t0 = fmaf(wh[j], hs[0][j], t0);
            t1 = fmaf(wh[j], hs[1][j], t1);
        }
        s0 = s0 + t0;                           // ... + h@W_hh.T
        s1 = s1 + t1;
        s0 = s0 + bhh;                          // ... + b_hh
        s1 = s1 + bhh;

        float a0, a1;
        if (wave == 2) {                        // gates 128..191: g-gate (tanh)
            a0 = tanhf(s0); a1 = tanhf(s1);
        } else {                                // i, f, o gates (sigmoid)
            a0 = 1.0f / (1.0f + expf(-s0));
            a1 = 1.0f / (1.0f + expf(-s1));
        }
        gb[0][g] = a0;
        gb[1][g] = a1;

        __syncthreads();   // A: gates ready; reads of xs[cb]/hs done

        if (wave < 2) {
            // ---- tail: cell update + FC + log_softmax + argmax ----
            const int b = wave;
            const float ig = gb[b][lane];
            const float fg = gb[b][64 + lane];
            const float gg = gb[b][128 + lane];
            const float og = gb[b][192 + lane];
            const float m1 = fg * cst;          // no contraction (pragma)
            const float m2 = ig * gg;
            cst = m1 + m2;
            const float h = og * tanhf(cst);
            hs[b][lane] = h;                    // same-wave LDS, lockstep-safe

            float l = 0.0f;
            if (lane < NCLS) {
#pragma unroll
                for (int j = 0; j < 64; ++j)    // h @ W_fc.T, sequential k
                    l = fmaf(hs[b][j], wfcT[j][lane], l);
                l = l + bfcs[lane];
            }
            const float l0 = __shfl(l, 0, 64);
            const float l1 = __shfl(l, 1, 64);
            const float l2 = __shfl(l, 2, 64);
            const float l3 = __shfl(l, 3, 64);
            const float l4 = __shfl(l, 4, 64);

            float m = l0;
            m = fmaxf(m, l1); m = fmaxf(m, l2);
            m = fmaxf(m, l3); m = fmaxf(m, l4);
            const float sh0 = l0 - m, sh1 = l1 - m, sh2 = l2 - m,
                        sh3 = l3 - m, sh4 = l4 - m;
            float ss = expf(sh0);
            ss = ss + expf(sh1); ss = ss + expf(sh2);
            ss = ss + expf(sh3); ss = ss + expf(sh4);
            const float lg = logf(ss);
            const float p0 = sh0 - lg, p1 = sh1 - lg, p2 = sh2 - lg,
                        p3 = sh3 - lg, p4 = sh4 - lg;

            // argmax over the ROUNDED logp values (np.argmax semantics)
            if (lane == 0) {
                int best = 0; float bv = p0;
                if (p1 > bv) { bv = p1; best = 1; }
                if (p2 > bv) { bv = p2; best = 2; }
                if (p3 > bv) { bv = p3; best = 3; }
                if (p4 > bv) { bv = p4; best = 4; }
                sIdx[b] = best;
            }
            if (lane < NCLS) {
                const float pv = (lane == 0) ? p0 : (lane == 1) ? p1
                               : (lane == 2) ? p2 : (lane == 3) ? p3 : p4;
                out[((size_t)(b0 + b) * TT + t) * NCLS + lane] = pv;
            }
        } else if (t + 1 < TT) {
            if (wave == 2) xs[nb][0][lane] = xn;
            else           xs[nb][1][lane] = xn;
        }

        __syncthreads();   // B: hs, sIdx, xs[nb] ready for t+1
    }
}

extern "C" void kernel_launch(void* const* d_in, const int* in_sizes, int n_in,
                              void* d_out, int out_size, void* d_ws, size_t ws_size,
                              hipStream_t stream) {
    const float* x    = (const float*)d_in[0];
    // d_in[1] = x_lengths (all == T), d_in[2] = edge_list : unused by reference
    const float* W_ih = (const float*)d_in[3];
    const float* W_hh = (const float*)d_in[4];
    const float* b_ih = (const float*)d_in[5];
    const float* b_hh = (const float*)d_in[6];
    const float* W_fc = (const float*)d_in[7];
    const float* b_fc = (const float*)d_in[8];
    const float* emb  = (const float*)d_in[9];
    float* out = (float*)d_out;

    ar_lstm_seq<<<512, 256, 0, stream>>>(x, W_ih, W_hh, b_ih, b_hh,
                                         W_fc, b_fc, emb, out);
}